// Round 5
// baseline (372.165 us; speedup 1.0000x reference)
//
#include <hip/hip_runtime.h>

// Dice coefficient: argmax over C=4 classes per pixel + histogram counts.
// Shapes fixed by the problem: B=32, C=4, H=W=512.
constexpr int kHW     = 512 * 512;  // 262144 pixels per plane (65536 float4-groups)
constexpr int kC      = 4;
constexpr int kBlocks = 2048;       // 64 blocks per batch plane, exact cover

// ws layout: u64 part[2048][3] (packed predp/truep/tpp), then u32 ticket at
// byte 49152. Partials are fully overwritten; ticket relies on the harness's
// deterministic 0xAA poison (or zeros on a fresh buffer) — both accepted.

typedef float vfloat4 __attribute__((ext_vector_type(4)));
typedef int   vint4   __attribute__((ext_vector_type(4)));

__device__ __forceinline__ vfloat4 nt4f(const float* p) {
    return __builtin_nontemporal_load((const vfloat4*)p);
}
__device__ __forceinline__ vint4 nt4i(const int* p) {
    return __builtin_nontemporal_load((const vint4*)p);
}

__device__ __forceinline__ void do_group(const vfloat4& v0, const vfloat4& v1,
                                         const vfloat4& v2, const vfloat4& v3,
                                         const vint4& t,
                                         unsigned long long& predp,
                                         unsigned long long& truep,
                                         unsigned long long& tpp) {
    // First-max-wins argmax (strict >) matches jnp.argmax semantics.
    #define DO_PIXEL(f)                                            \
    {                                                              \
        int   pred = 0;                                            \
        float best = v0.f;                                         \
        if (v1.f > best) { best = v1.f; pred = 1; }                \
        if (v2.f > best) { best = v2.f; pred = 2; }                \
        if (v3.f > best) { best = v3.f; pred = 3; }                \
        predp += 1ull << (pred << 4);                              \
        truep += 1ull << (t.f << 4);                               \
        if (pred == t.f) tpp += 1ull << (pred << 4);               \
    }
    DO_PIXEL(x) DO_PIXEL(y) DO_PIXEL(z) DO_PIXEL(w)
    #undef DO_PIXEL
}

// 2048 blocks x 256 threads x 4 groups/thread = 2,097,152 groups (exact cover).
// Non-temporal loads: zero-reuse stream must not allocate into L3 and evict
// the restore-warmed input ahead of itself. Last block (ticket) runs the
// final reduction — no second dispatch.
__global__ __launch_bounds__(256)
void dice_fused_kernel(const int* __restrict__ tm, const float* __restrict__ outp,
                       unsigned long long* __restrict__ part,
                       unsigned* __restrict__ ticket,
                       float* __restrict__ out) {
    const int b  = blockIdx.x >> 6;                          // 64 blocks / plane
    const int g0 = ((blockIdx.x & 63) << 10) + threadIdx.x;  // group idx in plane

    const float* pb = outp + (size_t)b * kC * kHW;
    const int*   tb = tm   + (size_t)b * kHW;

    vfloat4 a0, a1, a2, a3, c0, c1, c2, c3;
    vint4   ta, tc;

    #define LOAD(k, r0, r1, r2, r3, rt)                    \
    {                                                      \
        const int rem = (g0 + ((k) << 8)) << 2;            \
        r0 = nt4f(pb + rem);                               \
        r1 = nt4f(pb + kHW + rem);                         \
        r2 = nt4f(pb + 2 * kHW + rem);                     \
        r3 = nt4f(pb + 3 * kHW + rem);                     \
        rt = nt4i(tb + rem);                               \
    }

    unsigned long long predp = 0, truep = 0, tpp = 0;

    LOAD(0, a0, a1, a2, a3, ta)
    LOAD(1, c0, c1, c2, c3, tc)
    do_group(a0, a1, a2, a3, ta, predp, truep, tpp);
    LOAD(2, a0, a1, a2, a3, ta)
    do_group(c0, c1, c2, c3, tc, predp, truep, tpp);
    LOAD(3, c0, c1, c2, c3, tc)
    do_group(a0, a1, a2, a3, ta, predp, truep, tpp);
    do_group(c0, c1, c2, c3, tc, predp, truep, tpp);
    #undef LOAD

    // Wave-64 butterfly reduction (fields <= 1024/wave, fits u16).
    for (int off = 32; off > 0; off >>= 1) {
        predp += __shfl_down(predp, off);
        truep += __shfl_down(truep, off);
        tpp   += __shfl_down(tpp, off);
    }

    __shared__ unsigned long long s[3][4];
    __shared__ int sLast;
    const int lane = threadIdx.x & 63;
    const int wave = threadIdx.x >> 6;
    if (lane == 0) { s[0][wave] = predp; s[1][wave] = truep; s[2][wave] = tpp; }
    __syncthreads();

    if (threadIdx.x == 0) {
        // Block totals <= 4096 per u16 field.
        unsigned long long P = s[0][0] + s[0][1] + s[0][2] + s[0][3];
        unsigned long long T = s[1][0] + s[1][1] + s[1][2] + s[1][3];
        unsigned long long Q = s[2][0] + s[2][1] + s[2][2] + s[2][3];
        unsigned long long* p = part + (size_t)blockIdx.x * 3;
        __hip_atomic_store(&p[0], P, __ATOMIC_RELAXED, __HIP_MEMORY_SCOPE_AGENT);
        __hip_atomic_store(&p[1], T, __ATOMIC_RELAXED, __HIP_MEMORY_SCOPE_AGENT);
        __hip_atomic_store(&p[2], Q, __ATOMIC_RELEASE, __HIP_MEMORY_SCOPE_AGENT);
        // Ticket starts at 0xAAAAAAAA (harness poison) or 0 (fresh buffer).
        const unsigned old = __hip_atomic_fetch_add(ticket, 1u, __ATOMIC_ACQ_REL,
                                                    __HIP_MEMORY_SCOPE_AGENT);
        sLast = (old == (unsigned)(kBlocks - 1)) ||
                (old == 0xAAAAAAAAu + (unsigned)(kBlocks - 1));
    }
    __syncthreads();
    if (!sLast) return;

    // ---- Final phase: last block sums 2048 packed partials (8/thread;
    // packed sums <= 8*4096 = 32768, still fits u16), unpacks, divides. ----
    unsigned long long P = 0, T = 0, Q = 0;
    #pragma unroll
    for (int i = 0; i < 8; ++i) {
        const unsigned long long* p = part + ((size_t)threadIdx.x + (i << 8)) * 3;
        P += __hip_atomic_load(&p[0], __ATOMIC_RELAXED, __HIP_MEMORY_SCOPE_AGENT);
        T += __hip_atomic_load(&p[1], __ATOMIC_RELAXED, __HIP_MEMORY_SCOPE_AGENT);
        Q += __hip_atomic_load(&p[2], __ATOMIC_RELAXED, __HIP_MEMORY_SCOPE_AGENT);
    }

    unsigned pc[4], tc4[4], qc[4];
    #pragma unroll
    for (int c = 0; c < 4; ++c) {
        pc[c]  = (unsigned)((P >> (c * 16)) & 0xFFFF);
        tc4[c] = (unsigned)((T >> (c * 16)) & 0xFFFF);
        qc[c]  = (unsigned)((Q >> (c * 16)) & 0xFFFF);
    }
    for (int off = 32; off > 0; off >>= 1) {
        #pragma unroll
        for (int c = 0; c < 4; ++c) {
            pc[c]  += __shfl_down(pc[c], off);
            tc4[c] += __shfl_down(tc4[c], off);
            qc[c]  += __shfl_down(qc[c], off);
        }
    }

    __shared__ unsigned f[12][4];
    if (lane == 0) {
        #pragma unroll
        for (int c = 0; c < 4; ++c) {
            f[c][wave]     = pc[c];
            f[4 + c][wave] = tc4[c];
            f[8 + c][wave] = qc[c];
        }
    }
    __syncthreads();

    if (threadIdx.x >= 1 && threadIdx.x < 4) {   // classes 1..3 (skip background)
        const int c = (int)threadIdx.x;
        const float pcnt = (float)(f[c][0] + f[c][1] + f[c][2] + f[c][3]);
        const float tcnt = (float)(f[4 + c][0] + f[4 + c][1] + f[4 + c][2] + f[4 + c][3]);
        const float tp   = (float)(f[8 + c][0] + f[8 + c][1] + f[8 + c][2] + f[8 + c][3]);
        out[c - 1] = 2.0f * tp / (pcnt + tcnt);
    }
}

extern "C" void kernel_launch(void* const* d_in, const int* in_sizes, int n_in,
                              void* d_out, int out_size, void* d_ws, size_t ws_size,
                              hipStream_t stream) {
    const int*   tm = (const int*)d_in[0];    // true_masks [B,H,W] int32
    const float* op = (const float*)d_in[1];  // out        [B,C,H,W] f32
    unsigned long long* part = (unsigned long long*)d_ws;
    unsigned* ticket = (unsigned*)((char*)d_ws + (size_t)kBlocks * 3 * sizeof(unsigned long long));

    dice_fused_kernel<<<kBlocks, 256, 0, stream>>>(tm, op, part, ticket, (float*)d_out);
}

// Round 6
// 213.294 us; speedup vs baseline: 1.7448x; 1.7448x over previous
//
#include <hip/hip_runtime.h>

// Dice coefficient: argmax over C=4 classes per pixel + histogram counts.
// Shapes fixed by the problem: B=32, C=4, H=W=512.
//
// R5 lesson: NO device-scope release/acquire atomics in the hot kernel
// (agent-scope acq/rel forces L2 writeback/invalidate -> 3.6x regression),
// NO non-temporal loads (read-once stream is already L3-warm; nt disables
// the hit path). Plain per-block stores + tiny second dispatch is fastest.
constexpr int kHW = 512 * 512;   // 262144 pixels per plane (65536 float4-groups)
constexpr int kC  = 4;
constexpr int kBlocks = 2048;    // 64 blocks per batch plane

// ws layout: per-block packed partials, u64[3] per block (predp, truep, tpp).
// Fully overwritten every launch -> no init needed despite 0xAA poison.

__device__ __forceinline__ void do_group(const float4& v0, const float4& v1,
                                         const float4& v2, const float4& v3,
                                         const int4& t,
                                         unsigned long long& predp,
                                         unsigned long long& truep,
                                         unsigned long long& tpp) {
    // First-max-wins argmax (strict >) matches jnp.argmax semantics.
    #define DO_PIXEL(f, tf)                                        \
    {                                                              \
        int   pred = 0;                                            \
        float best = v0.f;                                         \
        if (v1.f > best) { best = v1.f; pred = 1; }                \
        if (v2.f > best) { best = v2.f; pred = 2; }                \
        if (v3.f > best) { best = v3.f; pred = 3; }                \
        predp += 1ull << (pred << 4);                              \
        truep += 1ull << (t.tf << 4);                              \
        if (pred == t.tf) tpp += 1ull << (pred << 4);              \
    }
    DO_PIXEL(x, x) DO_PIXEL(y, y) DO_PIXEL(z, z) DO_PIXEL(w, w)
    #undef DO_PIXEL
}

// 2048 blocks x 256 threads x 4 groups/thread = 2,097,152 groups (exact cover).
// Each block covers 1024 consecutive groups in one batch plane (b uniform).
__global__ __launch_bounds__(256)
void dice_count_kernel(const int* __restrict__ tm, const float* __restrict__ outp,
                       unsigned long long* __restrict__ part) {
    const int b  = blockIdx.x >> 6;                          // 64 blocks / plane
    const int g0 = ((blockIdx.x & 63) << 10) + threadIdx.x;  // group idx in plane

    const float* pb = outp + (size_t)b * kC * kHW;
    const int*   tb = tm   + (size_t)b * kHW;

    float4 a0, a1, a2, a3, b0, b1, b2, b3;
    int4   ta, tbm;

    #define LOAD(k, r0, r1, r2, r3, rt)                    \
    {                                                      \
        const int rem = (g0 + ((k) << 8)) << 2;            \
        r0 = *(const float4*)(pb + rem);                   \
        r1 = *(const float4*)(pb + kHW + rem);             \
        r2 = *(const float4*)(pb + 2 * kHW + rem);         \
        r3 = *(const float4*)(pb + 3 * kHW + rem);         \
        rt = *(const int4*)(tb + rem);                     \
    }

    unsigned long long predp = 0, truep = 0, tpp = 0;

    LOAD(0, a0, a1, a2, a3, ta)
    LOAD(1, b0, b1, b2, b3, tbm)
    do_group(a0, a1, a2, a3, ta, predp, truep, tpp);
    LOAD(2, a0, a1, a2, a3, ta)
    do_group(b0, b1, b2, b3, tbm, predp, truep, tpp);
    LOAD(3, b0, b1, b2, b3, tbm)
    do_group(a0, a1, a2, a3, ta, predp, truep, tpp);
    do_group(b0, b1, b2, b3, tbm, predp, truep, tpp);
    #undef LOAD

    // Wave-64 butterfly reduction (fields <= 1024/wave, fits u16).
    for (int off = 32; off > 0; off >>= 1) {
        predp += __shfl_down(predp, off);
        truep += __shfl_down(truep, off);
        tpp   += __shfl_down(tpp, off);
    }

    __shared__ unsigned long long s[3][4];
    const int lane = threadIdx.x & 63;
    const int wave = threadIdx.x >> 6;
    if (lane == 0) { s[0][wave] = predp; s[1][wave] = truep; s[2][wave] = tpp; }
    __syncthreads();

    if (threadIdx.x == 0) {
        // Block totals <= 4096 per u16 field. Plain stores, no atomics/init.
        unsigned long long* p = part + (size_t)blockIdx.x * 3;
        p[0] = s[0][0] + s[0][1] + s[0][2] + s[0][3];
        p[1] = s[1][0] + s[1][1] + s[1][2] + s[1][3];
        p[2] = s[2][0] + s[2][1] + s[2][2] + s[2][3];
    }
}

// One block, 256 threads: sum 2048 packed partials (8/thread, packed sums
// <= 8*4096 = 32768 — still fits u16), unpack to u32, reduce, divide.
__global__ __launch_bounds__(256)
void dice_final_kernel(const unsigned long long* __restrict__ part,
                       float* __restrict__ out) {
    unsigned long long P = 0, T = 0, Q = 0;
    #pragma unroll
    for (int i = 0; i < 8; ++i) {
        const unsigned long long* p = part + ((size_t)threadIdx.x + (i << 8)) * 3;
        P += p[0]; T += p[1]; Q += p[2];
    }

    unsigned pc[4], tc[4], qc[4];
    #pragma unroll
    for (int c = 0; c < 4; ++c) {
        pc[c] = (unsigned)((P >> (c * 16)) & 0xFFFF);
        tc[c] = (unsigned)((T >> (c * 16)) & 0xFFFF);
        qc[c] = (unsigned)((Q >> (c * 16)) & 0xFFFF);
    }
    for (int off = 32; off > 0; off >>= 1) {
        #pragma unroll
        for (int c = 0; c < 4; ++c) {
            pc[c] += __shfl_down(pc[c], off);
            tc[c] += __shfl_down(tc[c], off);
            qc[c] += __shfl_down(qc[c], off);
        }
    }

    __shared__ unsigned s[12][4];
    const int lane = threadIdx.x & 63;
    const int wave = threadIdx.x >> 6;
    if (lane == 0) {
        #pragma unroll
        for (int c = 0; c < 4; ++c) {
            s[c][wave]     = pc[c];
            s[4 + c][wave] = tc[c];
            s[8 + c][wave] = qc[c];
        }
    }
    __syncthreads();

    if (threadIdx.x >= 1 && threadIdx.x < 4) {   // classes 1..3 (skip background)
        const int c = (int)threadIdx.x;
        const float pcnt = (float)(s[c][0] + s[c][1] + s[c][2] + s[c][3]);
        const float tcnt = (float)(s[4 + c][0] + s[4 + c][1] + s[4 + c][2] + s[4 + c][3]);
        const float tp   = (float)(s[8 + c][0] + s[8 + c][1] + s[8 + c][2] + s[8 + c][3]);
        out[c - 1] = 2.0f * tp / (pcnt + tcnt);
    }
}

extern "C" void kernel_launch(void* const* d_in, const int* in_sizes, int n_in,
                              void* d_out, int out_size, void* d_ws, size_t ws_size,
                              hipStream_t stream) {
    const int*   tm = (const int*)d_in[0];    // true_masks [B,H,W] int32
    const float* op = (const float*)d_in[1];  // out        [B,C,H,W] f32
    unsigned long long* part = (unsigned long long*)d_ws;

    dice_count_kernel<<<kBlocks, 256, 0, stream>>>(tm, op, part);
    dice_final_kernel<<<1, 256, 0, stream>>>(part, (float*)d_out);
}